// Round 1
// baseline (1055.294 us; speedup 1.0000x reference)
//
#include <hip/hip_runtime.h>
#include <hip/hip_bf16.h>

#define N_NODES 100000
#define E_EDGES 1600000
#define FDIM 128
#define NGRAPH 256
#define SCAN_CHUNK 1024
#define NSCANBLK ((N_NODES + SCAN_CHUNK - 1) / SCAN_CHUNK)   // 98

// ---------------- preprocessing ----------------

__global__ void initk(int* __restrict__ degInt, float* __restrict__ stats) {
    int i = blockIdx.x * blockDim.x + threadIdx.x;
    if (i < N_NODES) degInt[i] = 1;            // self-loop
    if (i < 768) stats[i] = 0.0f;              // 3 layers x (sum[128], sumsq[128])
}

__global__ void degk(const int* __restrict__ ei, int* __restrict__ degInt) {
    int e = blockIdx.x * blockDim.x + threadIdx.x;
    if (e < E_EDGES) atomicAdd(&degInt[ei[E_EDGES + e]], 1);
}

__global__ void dinvk(const int* __restrict__ degInt, float* __restrict__ dinv) {
    int i = blockIdx.x * blockDim.x + threadIdx.x;
    if (i < N_NODES) dinv[i] = rsqrtf((float)degInt[i]);
}

__global__ __launch_bounds__(256) void scan1(const int* __restrict__ degInt,
                                             int* __restrict__ offs,
                                             int* __restrict__ blockSums) {
    __shared__ int sdata[256];
    int tid = threadIdx.x;
    int base = blockIdx.x * SCAN_CHUNK + tid * 4;
    int v[4];
#pragma unroll
    for (int j = 0; j < 4; j++) {
        int idx = base + j;
        v[j] = (idx < N_NODES) ? (degInt[idx] - 1) : 0;   // in-edge count (no self-loop)
    }
    int tsum = v[0] + v[1] + v[2] + v[3];
    sdata[tid] = tsum;
    __syncthreads();
    for (int st = 1; st < 256; st <<= 1) {
        int x = sdata[tid];
        int y = (tid >= st) ? sdata[tid - st] : 0;
        __syncthreads();
        sdata[tid] = x + y;
        __syncthreads();
    }
    int texcl = sdata[tid] - tsum;
    if (tid == 255) blockSums[blockIdx.x] = sdata[255];
    int run = texcl;
#pragma unroll
    for (int j = 0; j < 4; j++) {
        int idx = base + j;
        if (idx < N_NODES) offs[idx] = run;
        run += v[j];
    }
}

__global__ __launch_bounds__(128) void scan2(const int* __restrict__ blockSums,
                                             int* __restrict__ blockBase, int nblocks) {
    __shared__ int sdata[128];
    int tid = threadIdx.x;
    int v = (tid < nblocks) ? blockSums[tid] : 0;
    sdata[tid] = v;
    __syncthreads();
    for (int st = 1; st < 128; st <<= 1) {
        int x = sdata[tid];
        int y = (tid >= st) ? sdata[tid - st] : 0;
        __syncthreads();
        sdata[tid] = x + y;
        __syncthreads();
    }
    if (tid < nblocks) blockBase[tid] = sdata[tid] - v;
}

__global__ void scan3(int* __restrict__ offs, const int* __restrict__ blockBase,
                      int* __restrict__ cursor) {
    int i = blockIdx.x * blockDim.x + threadIdx.x;
    if (i < N_NODES) {
        int o = offs[i] + blockBase[i / SCAN_CHUNK];
        offs[i] = o;
        cursor[i] = o;
    }
}

__global__ void fillcsr(const int* __restrict__ ei, const float* __restrict__ dinv,
                        int* __restrict__ cursor, int* __restrict__ csr_src,
                        float* __restrict__ csr_coef) {
    int e = blockIdx.x * blockDim.x + threadIdx.x;
    if (e < E_EDGES) {
        int s = ei[e];
        int d = ei[E_EDGES + e];
        int slot = atomicAdd(&cursor[d], 1);
        csr_src[slot] = s;
        csr_coef[slot] = dinv[s] * dinv[d];
    }
}

// ---------------- GEMM: out[N,128] = A[N,128] @ W[128,128] ----------------
// 256 threads: 64 rows x 128 cols per block; thread = 8 rows x 4 cols.

__global__ __launch_bounds__(256, 2) void gemm128(const float* __restrict__ A,
                                                  const float* __restrict__ Wm,
                                                  float* __restrict__ out) {
    __shared__ float sW[128 * 128];   // 64 KB
    __shared__ float sX[64 * 32];     // 8 KB (k-chunk)
    int tid = threadIdx.x;
    {
        const float4* W4 = (const float4*)Wm;
        float4* sW4 = (float4*)sW;
#pragma unroll
        for (int i = 0; i < 16; i++) sW4[tid + 256 * i] = W4[tid + 256 * i];
    }
    int row0 = blockIdx.x * 64;
    int cg = tid & 31;    // col group: cols 4*cg..4*cg+3
    int rg = tid >> 5;    // row group: rows rg*8..rg*8+7
    float4 acc[8];
#pragma unroll
    for (int r = 0; r < 8; r++) acc[r] = make_float4(0.f, 0.f, 0.f, 0.f);
    const float4* A4 = (const float4*)A;
    float4* sX4 = (float4*)sX;
    const float4* sW4c = (const float4*)sW;

    for (int kk = 0; kk < 128; kk += 32) {
        __syncthreads();
#pragma unroll
        for (int j = 0; j < 2; j++) {
            int idx4 = tid * 2 + j;       // 0..511
            int r = idx4 >> 3;            // local row 0..63
            int cs = idx4 & 7;            // float4 within the 32-float k-chunk
            int grow = row0 + r;
            float4 val = make_float4(0.f, 0.f, 0.f, 0.f);
            if (grow < N_NODES) val = A4[grow * 32 + (kk >> 2) + cs];
            sX4[idx4] = val;
        }
        __syncthreads();
#pragma unroll
        for (int k = 0; k < 32; k++) {
            float4 w = sW4c[(kk + k) * 32 + cg];
#pragma unroll
            for (int r = 0; r < 8; r++) {
                float a = sX[(rg * 8 + r) * 32 + k];
                acc[r].x += a * w.x;
                acc[r].y += a * w.y;
                acc[r].z += a * w.z;
                acc[r].w += a * w.w;
            }
        }
    }
    float4* out4 = (float4*)out;
#pragma unroll
    for (int r = 0; r < 8; r++) {
        int grow = row0 + rg * 8 + r;
        if (grow < N_NODES) out4[grow * 32 + cg] = acc[r];
    }
}

// ---------------- edge aggregation (gather form) ----------------
// one node per block, thread = channel

__global__ __launch_bounds__(128) void agg(const float* __restrict__ t,
                                           const int* __restrict__ csr_src,
                                           const float* __restrict__ csr_coef,
                                           const int* __restrict__ offs,
                                           const int* __restrict__ degInt,
                                           const float* __restrict__ dinv,
                                           const float* __restrict__ bias,
                                           float* __restrict__ out) {
    int i = blockIdx.x;
    int c = threadIdx.x;
    float di = dinv[i];
    float acc = t[i * FDIM + c] * di * di;    // self-loop
    int start = offs[i];
    int cnt = degInt[i] - 1;
    int e = 0;
    for (; e + 4 <= cnt; e += 4) {
        int s0 = csr_src[start + e + 0];
        int s1 = csr_src[start + e + 1];
        int s2 = csr_src[start + e + 2];
        int s3 = csr_src[start + e + 3];
        float c0 = csr_coef[start + e + 0];
        float c1 = csr_coef[start + e + 1];
        float c2 = csr_coef[start + e + 2];
        float c3 = csr_coef[start + e + 3];
        acc += c0 * t[s0 * FDIM + c];
        acc += c1 * t[s1 * FDIM + c];
        acc += c2 * t[s2 * FDIM + c];
        acc += c3 * t[s3 * FDIM + c];
    }
    for (; e < cnt; e++) {
        int s = csr_src[start + e];
        float cf = csr_coef[start + e];
        acc += cf * t[s * FDIM + c];
    }
    out[i * FDIM + c] = acc + bias[c];
}

// ---------------- batchnorm ----------------

__global__ __launch_bounds__(128) void bnstats(const float* __restrict__ h,
                                               float* __restrict__ stats) {
    int c = threadIdx.x;
    float s = 0.f, s2 = 0.f;
    for (int r = blockIdx.x; r < N_NODES; r += gridDim.x) {
        float v = h[r * FDIM + c];
        s += v;
        s2 += v * v;
    }
    atomicAdd(&stats[c], s);
    atomicAdd(&stats[FDIM + c], s2);
}

__global__ __launch_bounds__(256) void bnrelu(float* __restrict__ h,
                                              const float* __restrict__ stats,
                                              const float* __restrict__ g,
                                              const float* __restrict__ be) {
    __shared__ float sScale[FDIM], sBias[FDIM];
    int tid = threadIdx.x;
    if (tid < FDIM) {
        float mean = stats[tid] * (1.0f / N_NODES);
        float var = stats[FDIM + tid] * (1.0f / N_NODES) - mean * mean;
        float sc = g[tid] * rsqrtf(var + 1e-5f);
        sScale[tid] = sc;
        sBias[tid] = be[tid] - mean * sc;
    }
    __syncthreads();
    float4* h4 = (float4*)h;
    int total4 = N_NODES * 32;
    for (int i = blockIdx.x * blockDim.x + tid; i < total4; i += gridDim.x * blockDim.x) {
        float4 v = h4[i];
        int c = (i & 31) * 4;
        v.x = fmaxf(v.x * sScale[c + 0] + sBias[c + 0], 0.f);
        v.y = fmaxf(v.y * sScale[c + 1] + sBias[c + 1], 0.f);
        v.z = fmaxf(v.z * sScale[c + 2] + sBias[c + 2], 0.f);
        v.w = fmaxf(v.w * sScale[c + 3] + sBias[c + 3], 0.f);
        h4[i] = v;
    }
}

// ---------------- pool + final linear (fused) ----------------

__global__ __launch_bounds__(128) void poolk(const float* __restrict__ h,
                                             const int* __restrict__ batch,
                                             const float* __restrict__ Wl,
                                             const float* __restrict__ bl,
                                             float* __restrict__ out) {
    int g = blockIdx.x;
    int c = threadIdx.x;
    // lower_bound(batch, g)
    int lo = 0, hi = N_NODES;
    while (lo < hi) { int m = (lo + hi) >> 1; if (batch[m] < g) lo = m + 1; else hi = m; }
    int start = lo;
    lo = start; hi = N_NODES;
    while (lo < hi) { int m = (lo + hi) >> 1; if (batch[m] < g + 1) lo = m + 1; else hi = m; }
    int end = lo;
    float s = 0.f;
    for (int r = start; r < end; r++) s += h[r * FDIM + c];
    float cnt = (float)(end - start);
    float v = (cnt > 0.f ? s / cnt : 0.f) * Wl[c];
    __shared__ float red[FDIM];
    red[c] = v;
    __syncthreads();
    for (int st = 64; st > 0; st >>= 1) {
        if (c < st) red[c] += red[c + st];
        __syncthreads();
    }
    if (c == 0) out[g] = red[0] + bl[0];
}

// ---------------- launch ----------------

extern "C" void kernel_launch(void* const* d_in, const int* in_sizes, int n_in,
                              void* d_out, int out_size, void* d_ws, size_t ws_size,
                              hipStream_t stream) {
    const float* x  = (const float*)d_in[0];
    const int* ei   = (const int*)d_in[1];
    const int* batch = (const int*)d_in[2];
    const float* W1 = (const float*)d_in[3];
    const float* b1 = (const float*)d_in[4];
    const float* g1 = (const float*)d_in[5];
    const float* be1 = (const float*)d_in[6];
    const float* W2 = (const float*)d_in[7];
    const float* b2 = (const float*)d_in[8];
    const float* g2 = (const float*)d_in[9];
    const float* be2 = (const float*)d_in[10];
    const float* W3 = (const float*)d_in[11];
    const float* b3 = (const float*)d_in[12];
    const float* g3 = (const float*)d_in[13];
    const float* be3 = (const float*)d_in[14];
    const float* Wl = (const float*)d_in[15];
    const float* bl = (const float*)d_in[16];
    float* out = (float*)d_out;

    char* ws = (char*)d_ws;
    size_t off = 0;
    auto alloc = [&](size_t bytes) -> char* {
        char* p = ws + off;
        off = (off + bytes + 255) & ~(size_t)255;
        return p;
    };
    int* degInt    = (int*)alloc(N_NODES * 4);
    float* dinv    = (float*)alloc(N_NODES * 4);
    int* offs      = (int*)alloc(N_NODES * 4);
    int* cursor    = (int*)alloc(N_NODES * 4);
    int* blockSums = (int*)alloc(NSCANBLK * 4);
    int* blockBase = (int*)alloc(NSCANBLK * 4);
    int* csr_src   = (int*)alloc((size_t)E_EDGES * 4);
    float* csr_coef = (float*)alloc((size_t)E_EDGES * 4);
    float* stats   = (float*)alloc(768 * 4);
    float* T       = (float*)alloc((size_t)N_NODES * FDIM * 4);
    float* H       = (float*)alloc((size_t)N_NODES * FDIM * 4);

    const int nb_nodes = (N_NODES + 255) / 256;   // 391
    const int nb_edges = (E_EDGES + 255) / 256;   // 6250
    const int nb_gemm = (N_NODES + 63) / 64;      // 1563

    // preprocessing
    initk<<<nb_nodes, 256, 0, stream>>>(degInt, stats);
    degk<<<nb_edges, 256, 0, stream>>>(ei, degInt);
    dinvk<<<nb_nodes, 256, 0, stream>>>(degInt, dinv);
    scan1<<<NSCANBLK, 256, 0, stream>>>(degInt, offs, blockSums);
    scan2<<<1, 128, 0, stream>>>(blockSums, blockBase, NSCANBLK);
    scan3<<<nb_nodes, 256, 0, stream>>>(offs, blockBase, cursor);
    fillcsr<<<nb_edges, 256, 0, stream>>>(ei, dinv, cursor, csr_src, csr_coef);

    // layer 1
    gemm128<<<nb_gemm, 256, 0, stream>>>(x, W1, T);
    agg<<<N_NODES, 128, 0, stream>>>(T, csr_src, csr_coef, offs, degInt, dinv, b1, H);
    bnstats<<<512, 128, 0, stream>>>(H, stats + 0);
    bnrelu<<<2048, 256, 0, stream>>>(H, stats + 0, g1, be1);

    // layer 2
    gemm128<<<nb_gemm, 256, 0, stream>>>(H, W2, T);
    agg<<<N_NODES, 128, 0, stream>>>(T, csr_src, csr_coef, offs, degInt, dinv, b2, H);
    bnstats<<<512, 128, 0, stream>>>(H, stats + 256);
    bnrelu<<<2048, 256, 0, stream>>>(H, stats + 256, g2, be2);

    // layer 3
    gemm128<<<nb_gemm, 256, 0, stream>>>(H, W3, T);
    agg<<<N_NODES, 128, 0, stream>>>(T, csr_src, csr_coef, offs, degInt, dinv, b3, H);
    bnstats<<<512, 128, 0, stream>>>(H, stats + 512);
    bnrelu<<<2048, 256, 0, stream>>>(H, stats + 512, g3, be3);

    // pool + linear
    poolk<<<NGRAPH, 128, 0, stream>>>(H, batch, Wl, bl, out);
}

// Round 2
// 824.032 us; speedup vs baseline: 1.2806x; 1.2806x over previous
//
#include <hip/hip_runtime.h>
#include <hip/hip_bf16.h>

#define N_NODES 100000
#define E_EDGES 1600000
#define FDIM 128
#define NGRAPH 256
#define SCAN_CHUNK 1024
#define NSCANBLK ((N_NODES + SCAN_CHUNK - 1) / SCAN_CHUNK)   // 98

__device__ __forceinline__ unsigned pack_bf16(float a, float b) {
    unsigned ua = __float_as_uint(a);
    unsigned ub = __float_as_uint(b);
    ua = ua + 0x7fffu + ((ua >> 16) & 1u);
    ub = ub + 0x7fffu + ((ub >> 16) & 1u);
    return (ua >> 16) | (ub & 0xffff0000u);
}
__device__ __forceinline__ float bf_lo(unsigned u) { return __uint_as_float(u << 16); }
__device__ __forceinline__ float bf_hi(unsigned u) { return __uint_as_float(u & 0xffff0000u); }

// ---------------- preprocessing ----------------

__global__ void initk(int* __restrict__ degInt, float* __restrict__ stats) {
    int i = blockIdx.x * blockDim.x + threadIdx.x;
    if (i < N_NODES) degInt[i] = 1;            // self-loop
    if (i < 768) stats[i] = 0.0f;              // 3 layers x (sum[128], sumsq[128])
}

__global__ void degk(const int* __restrict__ ei, int* __restrict__ degInt) {
    int e = blockIdx.x * blockDim.x + threadIdx.x;
    if (e < E_EDGES) atomicAdd(&degInt[ei[E_EDGES + e]], 1);
}

__global__ void dinvk(const int* __restrict__ degInt, float* __restrict__ dinv) {
    int i = blockIdx.x * blockDim.x + threadIdx.x;
    if (i < N_NODES) dinv[i] = rsqrtf((float)degInt[i]);
}

__global__ __launch_bounds__(256) void scan1(const int* __restrict__ degInt,
                                             int* __restrict__ offs,
                                             int* __restrict__ blockSums) {
    __shared__ int sdata[256];
    int tid = threadIdx.x;
    int base = blockIdx.x * SCAN_CHUNK + tid * 4;
    int v[4];
#pragma unroll
    for (int j = 0; j < 4; j++) {
        int idx = base + j;
        v[j] = (idx < N_NODES) ? (degInt[idx] - 1) : 0;   // in-edge count (no self-loop)
    }
    int tsum = v[0] + v[1] + v[2] + v[3];
    sdata[tid] = tsum;
    __syncthreads();
    for (int st = 1; st < 256; st <<= 1) {
        int x = sdata[tid];
        int y = (tid >= st) ? sdata[tid - st] : 0;
        __syncthreads();
        sdata[tid] = x + y;
        __syncthreads();
    }
    int texcl = sdata[tid] - tsum;
    if (tid == 255) blockSums[blockIdx.x] = sdata[255];
    int run = texcl;
#pragma unroll
    for (int j = 0; j < 4; j++) {
        int idx = base + j;
        if (idx < N_NODES) offs[idx] = run;
        run += v[j];
    }
}

__global__ __launch_bounds__(128) void scan2(const int* __restrict__ blockSums,
                                             int* __restrict__ blockBase, int nblocks) {
    __shared__ int sdata[128];
    int tid = threadIdx.x;
    int v = (tid < nblocks) ? blockSums[tid] : 0;
    sdata[tid] = v;
    __syncthreads();
    for (int st = 1; st < 128; st <<= 1) {
        int x = sdata[tid];
        int y = (tid >= st) ? sdata[tid - st] : 0;
        __syncthreads();
        sdata[tid] = x + y;
        __syncthreads();
    }
    if (tid < nblocks) blockBase[tid] = sdata[tid] - v;
}

__global__ void scan3(int* __restrict__ offs, const int* __restrict__ blockBase,
                      int* __restrict__ cursor) {
    int i = blockIdx.x * blockDim.x + threadIdx.x;
    if (i < N_NODES) {
        int o = offs[i] + blockBase[i / SCAN_CHUNK];
        offs[i] = o;
        cursor[i] = o;
    }
}

__global__ void fillcsr(const int* __restrict__ ei, const float* __restrict__ dinv,
                        int* __restrict__ cursor, int2* __restrict__ csr) {
    int e = blockIdx.x * blockDim.x + threadIdx.x;
    if (e < E_EDGES) {
        int s = ei[e];
        int d = ei[E_EDGES + e];
        int slot = atomicAdd(&cursor[d], 1);
        csr[slot] = make_int2(s, __float_as_int(dinv[s] * dinv[d]));
    }
}

// ---------------- GEMM: T_bf16[N,128] = act(A[N,128]) @ W[128,128] ----------------
// act = BN-affine + ReLU (fused) when BN=true. 256 threads: 64 rows x 128 cols.

template <bool BN>
__global__ __launch_bounds__(256, 2) void gemm128(const float* __restrict__ A,
                                                  const float* __restrict__ Wm,
                                                  const float* __restrict__ stats,
                                                  const float* __restrict__ g,
                                                  const float* __restrict__ be,
                                                  unsigned* __restrict__ outT) {
    __shared__ float sW[128 * 128];   // 64 KB
    __shared__ float sX[64 * 32];     // 8 KB (k-chunk)
    __shared__ float sScale[FDIM], sBias[FDIM];
    int tid = threadIdx.x;
    {
        const float4* W4 = (const float4*)Wm;
        float4* sW4 = (float4*)sW;
#pragma unroll
        for (int i = 0; i < 16; i++) sW4[tid + 256 * i] = W4[tid + 256 * i];
    }
    if (BN && tid < FDIM) {
        float mean = stats[tid] * (1.0f / N_NODES);
        float var = stats[FDIM + tid] * (1.0f / N_NODES) - mean * mean;
        float sc = g[tid] * rsqrtf(var + 1e-5f);
        sScale[tid] = sc;
        sBias[tid] = be[tid] - mean * sc;
    }
    int row0 = blockIdx.x * 64;
    int cg = tid & 31;    // col group: cols 4*cg..4*cg+3
    int rg = tid >> 5;    // row group: rows rg*8..rg*8+7
    float4 acc[8];
#pragma unroll
    for (int r = 0; r < 8; r++) acc[r] = make_float4(0.f, 0.f, 0.f, 0.f);
    const float4* A4 = (const float4*)A;
    float4* sX4 = (float4*)sX;
    const float4* sW4c = (const float4*)sW;

    for (int kk = 0; kk < 128; kk += 32) {
        __syncthreads();
#pragma unroll
        for (int j = 0; j < 2; j++) {
            int idx4 = tid * 2 + j;       // 0..511
            int r = idx4 >> 3;            // local row 0..63
            int cs = idx4 & 7;            // float4 within the 32-float k-chunk
            int grow = row0 + r;
            float4 val = make_float4(0.f, 0.f, 0.f, 0.f);
            if (grow < N_NODES) val = A4[grow * 32 + (kk >> 2) + cs];
            if (BN) {
                int ch = kk + cs * 4;
                val.x = fmaxf(val.x * sScale[ch + 0] + sBias[ch + 0], 0.f);
                val.y = fmaxf(val.y * sScale[ch + 1] + sBias[ch + 1], 0.f);
                val.z = fmaxf(val.z * sScale[ch + 2] + sBias[ch + 2], 0.f);
                val.w = fmaxf(val.w * sScale[ch + 3] + sBias[ch + 3], 0.f);
            }
            sX4[idx4] = val;
        }
        __syncthreads();
#pragma unroll
        for (int k4 = 0; k4 < 8; k4++) {          // 4 k's per iter, all b128 LDS reads
            float4 w0 = sW4c[(kk + k4 * 4 + 0) * 32 + cg];
            float4 w1 = sW4c[(kk + k4 * 4 + 1) * 32 + cg];
            float4 w2 = sW4c[(kk + k4 * 4 + 2) * 32 + cg];
            float4 w3 = sW4c[(kk + k4 * 4 + 3) * 32 + cg];
#pragma unroll
            for (int r = 0; r < 8; r++) {
                float4 a = sX4[(rg * 8 + r) * 8 + k4];
                acc[r].x += a.x * w0.x; acc[r].y += a.x * w0.y; acc[r].z += a.x * w0.z; acc[r].w += a.x * w0.w;
                acc[r].x += a.y * w1.x; acc[r].y += a.y * w1.y; acc[r].z += a.y * w1.z; acc[r].w += a.y * w1.w;
                acc[r].x += a.z * w2.x; acc[r].y += a.z * w2.y; acc[r].z += a.z * w2.z; acc[r].w += a.z * w2.w;
                acc[r].x += a.w * w3.x; acc[r].y += a.w * w3.y; acc[r].z += a.w * w3.z; acc[r].w += a.w * w3.w;
            }
        }
    }
#pragma unroll
    for (int r = 0; r < 8; r++) {
        int grow = row0 + rg * 8 + r;
        if (grow < N_NODES) {
            uint2 p;
            p.x = pack_bf16(acc[r].x, acc[r].y);
            p.y = pack_bf16(acc[r].z, acc[r].w);
            *((uint2*)(outT + (size_t)grow * 64 + cg * 2)) = p;
        }
    }
}

// ---------------- edge aggregation (gather, bf16 rows) ----------------
// one wave per node; lane handles channels (2*lane, 2*lane+1)

__global__ __launch_bounds__(256) void agg(const unsigned* __restrict__ t,
                                           const int2* __restrict__ csr,
                                           const int* __restrict__ offs,
                                           const int* __restrict__ degInt,
                                           const float* __restrict__ dinv,
                                           const float* __restrict__ bias,
                                           float* __restrict__ outH) {
    int lane = threadIdx.x & 63;
    int node = __builtin_amdgcn_readfirstlane(blockIdx.x * 4 + (threadIdx.x >> 6));
    float di = dinv[node];
    unsigned su = t[node * 64 + lane];
    float cs = di * di;
    float acc0 = bf_lo(su) * cs;
    float acc1 = bf_hi(su) * cs;
    int start = offs[node];
    int cnt = degInt[node] - 1;
    int e = 0;
    for (; e + 4 <= cnt; e += 4) {
        int2 e0 = csr[start + e + 0];
        int2 e1 = csr[start + e + 1];
        int2 e2 = csr[start + e + 2];
        int2 e3 = csr[start + e + 3];
        unsigned u0 = t[e0.x * 64 + lane];
        unsigned u1 = t[e1.x * 64 + lane];
        unsigned u2 = t[e2.x * 64 + lane];
        unsigned u3 = t[e3.x * 64 + lane];
        float c0 = __int_as_float(e0.y);
        float c1 = __int_as_float(e1.y);
        float c2 = __int_as_float(e2.y);
        float c3 = __int_as_float(e3.y);
        acc0 += c0 * bf_lo(u0); acc1 += c0 * bf_hi(u0);
        acc0 += c1 * bf_lo(u1); acc1 += c1 * bf_hi(u1);
        acc0 += c2 * bf_lo(u2); acc1 += c2 * bf_hi(u2);
        acc0 += c3 * bf_lo(u3); acc1 += c3 * bf_hi(u3);
    }
    for (; e < cnt; e++) {
        int2 ee = csr[start + e];
        unsigned u = t[ee.x * 64 + lane];
        float cf = __int_as_float(ee.y);
        acc0 += cf * bf_lo(u);
        acc1 += cf * bf_hi(u);
    }
    const float2* bias2 = (const float2*)bias;
    float2 b = bias2[lane];
    float2* out2 = (float2*)outH;
    out2[node * 64 + lane] = make_float2(acc0 + b.x, acc1 + b.y);
}

// ---------------- batchnorm stats ----------------

__global__ __launch_bounds__(128) void bnstats(const float* __restrict__ h,
                                               float* __restrict__ stats) {
    int c = threadIdx.x;
    float s = 0.f, s2 = 0.f;
    for (int r = blockIdx.x; r < N_NODES; r += gridDim.x) {
        float v = h[r * FDIM + c];
        s += v;
        s2 += v * v;
    }
    atomicAdd(&stats[c], s);
    atomicAdd(&stats[FDIM + c], s2);
}

// ---------------- pool + BN3/ReLU + final linear (fused) ----------------

__global__ __launch_bounds__(128) void poolk(const float* __restrict__ h,
                                             const int* __restrict__ batch,
                                             const float* __restrict__ stats,
                                             const float* __restrict__ g3,
                                             const float* __restrict__ be3,
                                             const float* __restrict__ Wl,
                                             const float* __restrict__ bl,
                                             float* __restrict__ out) {
    int g = blockIdx.x;
    int c = threadIdx.x;
    float mean = stats[c] * (1.0f / N_NODES);
    float var = stats[FDIM + c] * (1.0f / N_NODES) - mean * mean;
    float sc = g3[c] * rsqrtf(var + 1e-5f);
    float bi = be3[c] - mean * sc;
    // lower_bound(batch, g), lower_bound(batch, g+1)
    int lo = 0, hi = N_NODES;
    while (lo < hi) { int m = (lo + hi) >> 1; if (batch[m] < g) lo = m + 1; else hi = m; }
    int start = lo;
    lo = start; hi = N_NODES;
    while (lo < hi) { int m = (lo + hi) >> 1; if (batch[m] < g + 1) lo = m + 1; else hi = m; }
    int end = lo;
    float s = 0.f;
    for (int r = start; r < end; r++) s += fmaxf(h[r * FDIM + c] * sc + bi, 0.f);
    float cnt = (float)(end - start);
    float v = (cnt > 0.f ? s / cnt : 0.f) * Wl[c];
    __shared__ float red[FDIM];
    red[c] = v;
    __syncthreads();
    for (int st = 64; st > 0; st >>= 1) {
        if (c < st) red[c] += red[c + st];
        __syncthreads();
    }
    if (c == 0) out[g] = red[0] + bl[0];
}

// ---------------- launch ----------------

extern "C" void kernel_launch(void* const* d_in, const int* in_sizes, int n_in,
                              void* d_out, int out_size, void* d_ws, size_t ws_size,
                              hipStream_t stream) {
    const float* x  = (const float*)d_in[0];
    const int* ei   = (const int*)d_in[1];
    const int* batch = (const int*)d_in[2];
    const float* W1 = (const float*)d_in[3];
    const float* b1 = (const float*)d_in[4];
    const float* g1 = (const float*)d_in[5];
    const float* be1 = (const float*)d_in[6];
    const float* W2 = (const float*)d_in[7];
    const float* b2 = (const float*)d_in[8];
    const float* g2 = (const float*)d_in[9];
    const float* be2 = (const float*)d_in[10];
    const float* W3 = (const float*)d_in[11];
    const float* b3 = (const float*)d_in[12];
    const float* g3 = (const float*)d_in[13];
    const float* be3 = (const float*)d_in[14];
    const float* Wl = (const float*)d_in[15];
    const float* bl = (const float*)d_in[16];
    float* out = (float*)d_out;

    char* ws = (char*)d_ws;
    size_t off = 0;
    auto alloc = [&](size_t bytes) -> char* {
        char* p = ws + off;
        off = (off + bytes + 255) & ~(size_t)255;
        return p;
    };
    int* degInt    = (int*)alloc(N_NODES * 4);
    float* dinv    = (float*)alloc(N_NODES * 4);
    int* offs      = (int*)alloc(N_NODES * 4);
    int* cursor    = (int*)alloc(N_NODES * 4);
    int* blockSums = (int*)alloc(NSCANBLK * 4);
    int* blockBase = (int*)alloc(NSCANBLK * 4);
    int2* csr      = (int2*)alloc((size_t)E_EDGES * 8);
    float* stats   = (float*)alloc(768 * 4);
    unsigned* T16  = (unsigned*)alloc((size_t)N_NODES * 64 * 4);   // bf16 x2 per uint
    float* H       = (float*)alloc((size_t)N_NODES * FDIM * 4);

    const int nb_nodes = (N_NODES + 255) / 256;   // 391
    const int nb_edges = (E_EDGES + 255) / 256;   // 6250
    const int nb_gemm = (N_NODES + 63) / 64;      // 1563
    const int nb_agg = N_NODES / 4;               // 25000

    // preprocessing
    initk<<<nb_nodes, 256, 0, stream>>>(degInt, stats);
    degk<<<nb_edges, 256, 0, stream>>>(ei, degInt);
    dinvk<<<nb_nodes, 256, 0, stream>>>(degInt, dinv);
    scan1<<<NSCANBLK, 256, 0, stream>>>(degInt, offs, blockSums);
    scan2<<<1, 128, 0, stream>>>(blockSums, blockBase, NSCANBLK);
    scan3<<<nb_nodes, 256, 0, stream>>>(offs, blockBase, cursor);
    fillcsr<<<nb_edges, 256, 0, stream>>>(ei, dinv, cursor, csr);

    // layer 1
    gemm128<false><<<nb_gemm, 256, 0, stream>>>(x, W1, nullptr, nullptr, nullptr, T16);
    agg<<<nb_agg, 256, 0, stream>>>(T16, csr, offs, degInt, dinv, b1, H);
    bnstats<<<512, 128, 0, stream>>>(H, stats + 0);

    // layer 2 (BN1+ReLU fused into GEMM A-load)
    gemm128<true><<<nb_gemm, 256, 0, stream>>>(H, W2, stats + 0, g1, be1, T16);
    agg<<<nb_agg, 256, 0, stream>>>(T16, csr, offs, degInt, dinv, b2, H);
    bnstats<<<512, 128, 0, stream>>>(H, stats + 256);

    // layer 3
    gemm128<true><<<nb_gemm, 256, 0, stream>>>(H, W3, stats + 256, g2, be2, T16);
    agg<<<nb_agg, 256, 0, stream>>>(T16, csr, offs, degInt, dinv, b3, H);
    bnstats<<<512, 128, 0, stream>>>(H, stats + 512);

    // pool (BN3+ReLU fused) + linear
    poolk<<<NGRAPH, 128, 0, stream>>>(H, batch, stats + 512, g3, be3, Wl, bl, out);
}

// Round 3
// 543.958 us; speedup vs baseline: 1.9400x; 1.5149x over previous
//
#include <hip/hip_runtime.h>
#include <hip/hip_bf16.h>

#define N_NODES 100000
#define E_EDGES 1600000
#define FDIM 128
#define NGRAPH 256
#define SCAN_CHUNK 1024
#define NSCANBLK ((N_NODES + SCAN_CHUNK - 1) / SCAN_CHUNK)   // 98
#define LDSW 136   // padded bf16 row stride (128 + 8)

typedef __attribute__((ext_vector_type(8))) short bf16x8;
typedef __attribute__((ext_vector_type(4))) float f32x4;

__device__ __forceinline__ unsigned pack_bf16(float a, float b) {
    unsigned ua = __float_as_uint(a);
    unsigned ub = __float_as_uint(b);
    ua = ua + 0x7fffu + ((ua >> 16) & 1u);
    ub = ub + 0x7fffu + ((ub >> 16) & 1u);
    return (ua >> 16) | (ub & 0xffff0000u);
}
__device__ __forceinline__ unsigned short bf16_1(float a) {
    unsigned ua = __float_as_uint(a);
    ua = ua + 0x7fffu + ((ua >> 16) & 1u);
    return (unsigned short)(ua >> 16);
}
__device__ __forceinline__ float bf_lo(unsigned u) { return __uint_as_float(u << 16); }
__device__ __forceinline__ float bf_hi(unsigned u) { return __uint_as_float(u & 0xffff0000u); }

// ---------------- preprocessing ----------------

__global__ void initk(int* __restrict__ degInt, float* __restrict__ stats,
                      float* __restrict__ sums) {
    int i = blockIdx.x * blockDim.x + threadIdx.x;
    if (i < N_NODES) degInt[i] = 1;            // self-loop
    if (i < 768) stats[i] = 0.0f;              // 3 layers x (sum[128], sumsq[128])
    if (i < NGRAPH * FDIM) sums[i] = 0.0f;     // pooled sums
}

__global__ void degk(const int* __restrict__ ei, int* __restrict__ degInt) {
    int e = blockIdx.x * blockDim.x + threadIdx.x;
    if (e < E_EDGES) atomicAdd(&degInt[ei[E_EDGES + e]], 1);
}

__global__ void dinvk(const int* __restrict__ degInt, float* __restrict__ dinv) {
    int i = blockIdx.x * blockDim.x + threadIdx.x;
    if (i < N_NODES) dinv[i] = rsqrtf((float)degInt[i]);
}

__global__ __launch_bounds__(256) void scan1(const int* __restrict__ degInt,
                                             int* __restrict__ offs,
                                             int* __restrict__ blockSums) {
    __shared__ int sdata[256];
    int tid = threadIdx.x;
    int base = blockIdx.x * SCAN_CHUNK + tid * 4;
    int v[4];
#pragma unroll
    for (int j = 0; j < 4; j++) {
        int idx = base + j;
        v[j] = (idx < N_NODES) ? (degInt[idx] - 1) : 0;
    }
    int tsum = v[0] + v[1] + v[2] + v[3];
    sdata[tid] = tsum;
    __syncthreads();
    for (int st = 1; st < 256; st <<= 1) {
        int x = sdata[tid];
        int y = (tid >= st) ? sdata[tid - st] : 0;
        __syncthreads();
        sdata[tid] = x + y;
        __syncthreads();
    }
    int texcl = sdata[tid] - tsum;
    if (tid == 255) blockSums[blockIdx.x] = sdata[255];
    int run = texcl;
#pragma unroll
    for (int j = 0; j < 4; j++) {
        int idx = base + j;
        if (idx < N_NODES) offs[idx] = run;
        run += v[j];
    }
}

__global__ __launch_bounds__(128) void scan2(const int* __restrict__ blockSums,
                                             int* __restrict__ blockBase, int nblocks) {
    __shared__ int sdata[128];
    int tid = threadIdx.x;
    int v = (tid < nblocks) ? blockSums[tid] : 0;
    sdata[tid] = v;
    __syncthreads();
    for (int st = 1; st < 128; st <<= 1) {
        int x = sdata[tid];
        int y = (tid >= st) ? sdata[tid - st] : 0;
        __syncthreads();
        sdata[tid] = x + y;
        __syncthreads();
    }
    if (tid < nblocks) blockBase[tid] = sdata[tid] - v;
}

__global__ void scan3(int* __restrict__ offs, const int* __restrict__ blockBase,
                      int* __restrict__ cursor) {
    int i = blockIdx.x * blockDim.x + threadIdx.x;
    if (i < N_NODES) {
        int o = offs[i] + blockBase[i / SCAN_CHUNK];
        offs[i] = o;
        cursor[i] = o;
    }
}

__global__ void fillcsr(const int* __restrict__ ei, const float* __restrict__ dinv,
                        int* __restrict__ cursor, int2* __restrict__ csr) {
    int e = blockIdx.x * blockDim.x + threadIdx.x;
    if (e < E_EDGES) {
        int s = ei[e];
        int d = ei[E_EDGES + e];
        int slot = atomicAdd(&cursor[d], 1);
        csr[slot] = make_int2(s, __float_as_int(dinv[s] * dinv[d]));
    }
}

// W^T (bf16) precompute: Wt[widx][n][k] = bf16(W[k][n])
__global__ __launch_bounds__(256) void transposeW(const float* __restrict__ W1,
                                                  const float* __restrict__ W2,
                                                  const float* __restrict__ W3,
                                                  unsigned short* __restrict__ Wt) {
    int b = blockIdx.x;
    int widx = b >> 3;
    int n0 = (b & 7) * 16;
    const float* W = (widx == 0) ? W1 : (widx == 1) ? W2 : W3;
    unsigned short* dst = Wt + widx * 16384;
    int t = threadIdx.x;
    int n = n0 + (t & 15);
#pragma unroll
    for (int i = 0; i < 8; i++) {
        int k = (t >> 4) + i * 16;
        dst[n * 128 + k] = bf16_1(W[k * 128 + n]);
    }
}

// ---------------- MFMA GEMM: T_bf16[N,128] = act(A[N,128]) @ W ----------------
// 256 thr = 4 waves of 64x32 output; full K=128 staged in LDS once.

template <bool BN>
__global__ __launch_bounds__(256, 2) void gemmMF(const float* __restrict__ A,
                                                 const unsigned short* __restrict__ Wt,
                                                 const float* __restrict__ stats,
                                                 const float* __restrict__ g,
                                                 const float* __restrict__ be,
                                                 unsigned short* __restrict__ outT) {
    __shared__ unsigned short sA[64 * LDSW];
    __shared__ unsigned short sW[128 * LDSW];
    __shared__ float sScale[FDIM], sBias[FDIM];
    int tid = threadIdx.x;
    if (BN) {
        if (tid < FDIM) {
            float mean = stats[tid] * (1.0f / N_NODES);
            float var = stats[FDIM + tid] * (1.0f / N_NODES) - mean * mean;
            float sc = g[tid] * rsqrtf(var + 1e-5f);
            sScale[tid] = sc;
            sBias[tid] = be[tid] - mean * sc;
        }
        __syncthreads();
    }
    int row0 = blockIdx.x * 64;
    // stage W^T bf16 rows (contiguous k) into LDS
    {
        const uint4* Wt4 = (const uint4*)Wt;
#pragma unroll
        for (int i = 0; i < 8; i++) {
            int flat = tid + 256 * i;        // 0..2047
            int r = flat >> 4, c8 = flat & 15;
            uint4 v = Wt4[flat];
            *(uint4*)&sW[r * LDSW + c8 * 8] = v;
        }
    }
    // stage A (fp32 -> BN/ReLU -> bf16)
    {
        const float4* A4 = (const float4*)A;
#pragma unroll
        for (int i = 0; i < 8; i++) {
            int flat = tid + 256 * i;        // 0..2047
            int r = flat >> 5, c4 = flat & 31;
            int grow = row0 + r;
            float4 v = make_float4(0.f, 0.f, 0.f, 0.f);
            if (grow < N_NODES) v = A4[grow * 32 + c4];
            if (BN) {
                int ch = c4 * 4;
                v.x = fmaxf(v.x * sScale[ch + 0] + sBias[ch + 0], 0.f);
                v.y = fmaxf(v.y * sScale[ch + 1] + sBias[ch + 1], 0.f);
                v.z = fmaxf(v.z * sScale[ch + 2] + sBias[ch + 2], 0.f);
                v.w = fmaxf(v.w * sScale[ch + 3] + sBias[ch + 3], 0.f);
            }
            uint2 p;
            p.x = pack_bf16(v.x, v.y);
            p.y = pack_bf16(v.z, v.w);
            *(uint2*)&sA[r * LDSW + c4 * 4] = p;
        }
    }
    __syncthreads();

    int lane = tid & 63;
    int w = tid >> 6;         // wave id: cols w*32..w*32+31
    int rbase = lane & 15;
    int kgrp = lane >> 4;     // 0..3
    f32x4 acc[4][2];
#pragma unroll
    for (int mf = 0; mf < 4; mf++)
#pragma unroll
        for (int nf = 0; nf < 2; nf++) acc[mf][nf] = (f32x4){0.f, 0.f, 0.f, 0.f};

#pragma unroll
    for (int kk = 0; kk < 4; kk++) {
        int kb = kk * 32 + kgrp * 8;
        bf16x8 af[4], bfr[2];
#pragma unroll
        for (int mf = 0; mf < 4; mf++)
            af[mf] = *(const bf16x8*)&sA[(mf * 16 + rbase) * LDSW + kb];
#pragma unroll
        for (int nf = 0; nf < 2; nf++)
            bfr[nf] = *(const bf16x8*)&sW[(w * 32 + nf * 16 + rbase) * LDSW + kb];
#pragma unroll
        for (int mf = 0; mf < 4; mf++)
#pragma unroll
            for (int nf = 0; nf < 2; nf++)
                acc[mf][nf] = __builtin_amdgcn_mfma_f32_16x16x32_bf16(
                    af[mf], bfr[nf], acc[mf][nf], 0, 0, 0);
    }
    // epilogue: C/D layout col = lane&15, row = (lane>>4)*4 + j
#pragma unroll
    for (int mf = 0; mf < 4; mf++) {
#pragma unroll
        for (int nf = 0; nf < 2; nf++) {
            int col = w * 32 + nf * 16 + rbase;
#pragma unroll
            for (int j = 0; j < 4; j++) {
                int grow = row0 + mf * 16 + kgrp * 4 + j;
                if (grow < N_NODES) {
                    outT[(size_t)grow * FDIM + col] = bf16_1(acc[mf][nf][j]);
                }
            }
        }
    }
}

// ---------------- edge aggregation (gather, bf16 rows) ----------------

__global__ __launch_bounds__(256) void agg(const unsigned* __restrict__ t,
                                           const int2* __restrict__ csr,
                                           const int* __restrict__ offs,
                                           const int* __restrict__ degInt,
                                           const float* __restrict__ dinv,
                                           const float* __restrict__ bias,
                                           float* __restrict__ outH) {
    int lane = threadIdx.x & 63;
    int node = __builtin_amdgcn_readfirstlane(blockIdx.x * 4 + (threadIdx.x >> 6));
    float di = dinv[node];
    unsigned su = t[node * 64 + lane];
    float cs = di * di;
    float acc0 = bf_lo(su) * cs;
    float acc1 = bf_hi(su) * cs;
    int start = offs[node];
    int cnt = degInt[node] - 1;
    int e = 0;
    for (; e + 4 <= cnt; e += 4) {
        int2 e0 = csr[start + e + 0];
        int2 e1 = csr[start + e + 1];
        int2 e2 = csr[start + e + 2];
        int2 e3 = csr[start + e + 3];
        unsigned u0 = t[e0.x * 64 + lane];
        unsigned u1 = t[e1.x * 64 + lane];
        unsigned u2 = t[e2.x * 64 + lane];
        unsigned u3 = t[e3.x * 64 + lane];
        float c0 = __int_as_float(e0.y);
        float c1 = __int_as_float(e1.y);
        float c2 = __int_as_float(e2.y);
        float c3 = __int_as_float(e3.y);
        acc0 += c0 * bf_lo(u0); acc1 += c0 * bf_hi(u0);
        acc0 += c1 * bf_lo(u1); acc1 += c1 * bf_hi(u1);
        acc0 += c2 * bf_lo(u2); acc1 += c2 * bf_hi(u2);
        acc0 += c3 * bf_lo(u3); acc1 += c3 * bf_hi(u3);
    }
    for (; e < cnt; e++) {
        int2 ee = csr[start + e];
        unsigned u = t[ee.x * 64 + lane];
        float cf = __int_as_float(ee.y);
        acc0 += cf * bf_lo(u);
        acc1 += cf * bf_hi(u);
    }
    const float2* bias2 = (const float2*)bias;
    float2 b = bias2[lane];
    float2* out2 = (float2*)outH;
    out2[node * 64 + lane] = make_float2(acc0 + b.x, acc1 + b.y);
}

// ---------------- batchnorm stats ----------------

__global__ __launch_bounds__(256) void bnstats(const float* __restrict__ h,
                                               float* __restrict__ stats) {
    int tid = threadIdx.x;
    int c = tid & 127;
    int half = tid >> 7;
    float s = 0.f, s2 = 0.f;
#pragma unroll 4
    for (int r = blockIdx.x * 2 + half; r < N_NODES; r += 2048) {
        float v = h[r * FDIM + c];
        s += v;
        s2 += v * v;
    }
    __shared__ float red[256], red2[256];
    red[tid] = s;
    red2[tid] = s2;
    __syncthreads();
    if (tid < 128) {
        atomicAdd(&stats[c], red[tid] + red[tid + 128]);
        atomicAdd(&stats[FDIM + c], red2[tid] + red2[tid + 128]);
    }
}

// ---------------- pool phase 1: BN3+ReLU + segment-sum ----------------
// 64 sorted nodes per block; flush per-channel partial to sums on graph change.

__global__ __launch_bounds__(128) void poolsum(const float* __restrict__ h,
                                               const int* __restrict__ batch,
                                               const float* __restrict__ stats,
                                               const float* __restrict__ g3,
                                               const float* __restrict__ be3,
                                               float* __restrict__ sums) {
    int c = threadIdx.x;
    int base = blockIdx.x * 64;
    float mean = stats[c] * (1.0f / N_NODES);
    float var = stats[FDIM + c] * (1.0f / N_NODES) - mean * mean;
    float sc = g3[c] * rsqrtf(var + 1e-5f);
    float bi = be3[c] - mean * sc;
    __shared__ int sb[64];
    if (c < 64) {
        int idx = base + c;
        sb[c] = (idx < N_NODES) ? batch[idx] : -1;
    }
    __syncthreads();
    float acc = 0.f;
    int gcur = sb[0];
    for (int r = 0; r < 64; r++) {
        int idx = base + r;
        if (idx >= N_NODES) break;
        int gr = sb[r];
        if (gr != gcur) {
            atomicAdd(&sums[gcur * FDIM + c], acc);
            acc = 0.f;
            gcur = gr;
        }
        acc += fmaxf(h[(size_t)idx * FDIM + c] * sc + bi, 0.f);
    }
    atomicAdd(&sums[gcur * FDIM + c], acc);
}

// ---------------- pool phase 2: divide + final linear ----------------

__global__ __launch_bounds__(128) void finalk(const float* __restrict__ sums,
                                              const int* __restrict__ batch,
                                              const float* __restrict__ Wl,
                                              const float* __restrict__ bl,
                                              float* __restrict__ out) {
    int g = blockIdx.x;
    int c = threadIdx.x;
    int lo = 0, hi = N_NODES;
    while (lo < hi) { int m = (lo + hi) >> 1; if (batch[m] < g) lo = m + 1; else hi = m; }
    int start = lo;
    lo = start; hi = N_NODES;
    while (lo < hi) { int m = (lo + hi) >> 1; if (batch[m] < g + 1) lo = m + 1; else hi = m; }
    int cnt = lo - start;
    float v = sums[g * FDIM + c] / fmaxf((float)cnt, 1.0f) * Wl[c];
    __shared__ float red[FDIM];
    red[c] = v;
    __syncthreads();
    for (int st = 64; st > 0; st >>= 1) {
        if (c < st) red[c] += red[c + st];
        __syncthreads();
    }
    if (c == 0) out[g] = red[0] + bl[0];
}

// ---------------- launch ----------------

extern "C" void kernel_launch(void* const* d_in, const int* in_sizes, int n_in,
                              void* d_out, int out_size, void* d_ws, size_t ws_size,
                              hipStream_t stream) {
    const float* x  = (const float*)d_in[0];
    const int* ei   = (const int*)d_in[1];
    const int* batch = (const int*)d_in[2];
    const float* W1 = (const float*)d_in[3];
    const float* b1 = (const float*)d_in[4];
    const float* g1 = (const float*)d_in[5];
    const float* be1 = (const float*)d_in[6];
    const float* W2 = (const float*)d_in[7];
    const float* b2 = (const float*)d_in[8];
    const float* g2 = (const float*)d_in[9];
    const float* be2 = (const float*)d_in[10];
    const float* W3 = (const float*)d_in[11];
    const float* b3 = (const float*)d_in[12];
    const float* g3 = (const float*)d_in[13];
    const float* be3 = (const float*)d_in[14];
    const float* Wl = (const float*)d_in[15];
    const float* bl = (const float*)d_in[16];
    float* out = (float*)d_out;

    char* ws = (char*)d_ws;
    size_t off = 0;
    auto alloc = [&](size_t bytes) -> char* {
        char* p = ws + off;
        off = (off + bytes + 255) & ~(size_t)255;
        return p;
    };
    int* degInt    = (int*)alloc(N_NODES * 4);
    float* dinv    = (float*)alloc(N_NODES * 4);
    int* offs      = (int*)alloc(N_NODES * 4);
    int* cursor    = (int*)alloc(N_NODES * 4);
    int* blockSums = (int*)alloc(NSCANBLK * 4);
    int* blockBase = (int*)alloc(NSCANBLK * 4);
    int2* csr      = (int2*)alloc((size_t)E_EDGES * 8);
    float* stats   = (float*)alloc(768 * 4);
    float* sums    = (float*)alloc(NGRAPH * FDIM * 4);
    unsigned short* Wt = (unsigned short*)alloc(3 * 16384 * 2);
    unsigned short* T16 = (unsigned short*)alloc((size_t)N_NODES * FDIM * 2);
    float* H       = (float*)alloc((size_t)N_NODES * FDIM * 4);

    const int nb_nodes = (N_NODES + 255) / 256;   // 391
    const int nb_edges = (E_EDGES + 255) / 256;   // 6250
    const int nb_gemm = (N_NODES + 63) / 64;      // 1563
    const int nb_agg = N_NODES / 4;               // 25000
    const int nb_pool = (N_NODES + 63) / 64;      // 1563

    // preprocessing
    initk<<<nb_nodes, 256, 0, stream>>>(degInt, stats, sums);
    degk<<<nb_edges, 256, 0, stream>>>(ei, degInt);
    dinvk<<<nb_nodes, 256, 0, stream>>>(degInt, dinv);
    scan1<<<NSCANBLK, 256, 0, stream>>>(degInt, offs, blockSums);
    scan2<<<1, 128, 0, stream>>>(blockSums, blockBase, NSCANBLK);
    scan3<<<nb_nodes, 256, 0, stream>>>(offs, blockBase, cursor);
    fillcsr<<<nb_edges, 256, 0, stream>>>(ei, dinv, cursor, csr);
    transposeW<<<24, 256, 0, stream>>>(W1, W2, W3, Wt);

    // layer 1
    gemmMF<false><<<nb_gemm, 256, 0, stream>>>(x, Wt, nullptr, nullptr, nullptr, T16);
    agg<<<nb_agg, 256, 0, stream>>>((const unsigned*)T16, csr, offs, degInt, dinv, b1, H);
    bnstats<<<1024, 256, 0, stream>>>(H, stats + 0);

    // layer 2 (BN1+ReLU fused into GEMM A-stage)
    gemmMF<true><<<nb_gemm, 256, 0, stream>>>(H, Wt + 16384, stats + 0, g1, be1, T16);
    agg<<<nb_agg, 256, 0, stream>>>((const unsigned*)T16, csr, offs, degInt, dinv, b2, H);
    bnstats<<<1024, 256, 0, stream>>>(H, stats + 256);

    // layer 3
    gemmMF<true><<<nb_gemm, 256, 0, stream>>>(H, Wt + 32768, stats + 256, g2, be2, T16);
    agg<<<nb_agg, 256, 0, stream>>>((const unsigned*)T16, csr, offs, degInt, dinv, b3, H);
    bnstats<<<1024, 256, 0, stream>>>(H, stats + 512);

    // pool (BN3+ReLU fused) + linear
    poolsum<<<nb_pool, 128, 0, stream>>>(H, batch, stats + 512, g3, be3, sums);
    finalk<<<NGRAPH, 128, 0, stream>>>(sums, batch, Wl, bl, out);
}